// Round 14
// baseline (420.810 us; speedup 1.0000x reference)
//
#include <hip/hip_runtime.h>
#include <hip/hip_bf16.h>

#define HALF_ROWS 262144
#define TAU 0.04f
#define BT_OFF 1024
#define LIST_OFF (BT_OFF + 320 * 512 * 2)   // 1024 + 327680

typedef __attribute__((ext_vector_type(8))) short s16x8;
typedef __attribute__((ext_vector_type(4))) float f32x4;

__device__ __forceinline__ unsigned short f2bf(float f) {
  union { float f; unsigned u; } v; v.f = f;
  unsigned r = v.u + 0x7fffu + ((v.u >> 16) & 1u);   // RTNE
  return (unsigned short)(r >> 16);
}

__device__ __forceinline__ s16x8 cvt8(const f32x4& a, const f32x4& b) {
  union { int i[4]; s16x8 v; } u;
  asm("v_cvt_pk_bf16_f32 %0, %1, %2" : "=v"(u.i[0]) : "v"(a[0]), "v"(a[1]));
  asm("v_cvt_pk_bf16_f32 %0, %1, %2" : "=v"(u.i[1]) : "v"(a[2]), "v"(a[3]));
  asm("v_cvt_pk_bf16_f32 %0, %1, %2" : "=v"(u.i[2]) : "v"(b[0]), "v"(b[1]));
  asm("v_cvt_pk_bf16_f32 %0, %1, %2" : "=v"(u.i[3]) : "v"(b[2]), "v"(b[3]));
  return u.v;
}

// ---- prep: W1 -> Bf in MFMA B-fragment order [cb20][ks16][lane64][8] ---------
__global__ void moe_prep(const float* __restrict__ gw1, const float* __restrict__ aw1,
                         const float* __restrict__ bw1, unsigned short* __restrict__ Bf,
                         unsigned* __restrict__ cnt) {
  if (blockIdx.x == 0 && threadIdx.x == 0) *cnt = 0u;
  int idx = blockIdx.x * 512 + threadIdx.x;          // 320*512 = 163840
  int j = idx & 7, l = (idx >> 3) & 63, ks = (idx >> 9) & 15, cb = idx >> 13;
  int col = cb * 16 + (l & 15);
  int k = ks * 32 + ((l >> 4) << 3) + j;
  float v;
  if (col < 64)       v = gw1[k * 64 + col];
  else if (col < 192) v = aw1[k * 128 + (col - 64)];
  else                v = bw1[k * 128 + (col - 192)];
  Bf[idx] = f2bf(v);
}

// ---- main: NO LDS, NO barriers. 8 waves x (16 rows x 320 cols) ---------------
// Per chunk: 2 A-loads (1-deep prefetch) + 20 B-frag loads (L2, contiguous 1KB)
// + 20 MFMA. Waves never synchronize; compiler's per-register waits keep the
// CU memory queue full (convert-kernel structure with MFMAs embedded).
__global__ __launch_bounds__(512, 2) void moe_main(
    const float* __restrict__ x, const unsigned short* __restrict__ Bf,
    const float* __restrict__ gb1, const float* __restrict__ gw2, const float* __restrict__ gb2,
    const float* __restrict__ ab1, const float* __restrict__ aw2, const float* __restrict__ ab2,
    const float* __restrict__ bb1, const float* __restrict__ bw2, const float* __restrict__ bb2,
    float* __restrict__ out, unsigned* __restrict__ cnt, unsigned* __restrict__ list, int cap) {
  const int tid = threadIdx.x;
  const int w = tid >> 6, l = tid & 63;
  const int lo = l & 15, hi = l >> 4;
  const long r0 = (long)blockIdx.x * 128 + w * 16;
  const float* ap0 = x + (r0 + lo) * 256 + hi * 8;     // rows r0..r0+15, k-slice
  const float* ap1 = ap0 + (long)HALF_ROWS * 256;      // second batch half
  const unsigned short* bp = Bf + l * 8;

  f32x4 acc[20];
#pragma unroll
  for (int ct = 0; ct < 20; ++ct) acc[ct] = (f32x4){0.f, 0.f, 0.f, 0.f};

  f32x4 a0 = *(const f32x4*)ap0;
  f32x4 a1 = *(const f32x4*)(ap0 + 4);

#pragma unroll 1
  for (int kc = 0; kc < 16; ++kc) {
    f32x4 n0, n1;
    if (kc < 15) {                                     // prefetch next A chunk
      const float* np = (kc < 7) ? ap0 + (kc + 1) * 32 : ap1 + (kc - 7) * 32;
      n0 = *(const f32x4*)np;
      n1 = *(const f32x4*)(np + 4);
    }
    s16x8 af = cvt8(a0, a1);
    const unsigned short* bq = bp + ((size_t)kc << 9); // + ct*8192 per col-block
#pragma unroll
    for (int ct = 0; ct < 20; ++ct) {
      s16x8 bf = *(const s16x8*)(bq + ((size_t)ct << 13));
      acc[ct] = __builtin_amdgcn_mfma_f32_16x16x32_bf16(af, bf, acc[ct], 0, 0, 0);
    }
    a0 = n0; a1 = n1;
  }

  // ---- epilogue: wave-local, 16 rows x all 320 cols --------------------------
  float pg0[4] = {0,0,0,0}, pg1[4] = {0,0,0,0};
  float pa0[4] = {0,0,0,0}, pa1[4] = {0,0,0,0};
  float pq0[4] = {0,0,0,0}, pq1[4] = {0,0,0,0};
#pragma unroll
  for (int ct = 0; ct < 20; ++ct) {
    int col = ct * 16 + lo;
    float b1, w0, w1;
    if (ct < 4)       { b1 = gb1[col];        w0 = gw2[col * 2];        w1 = gw2[col * 2 + 1]; }
    else if (ct < 12) { int c = col - 64;  b1 = ab1[c]; w0 = aw2[c * 2]; w1 = aw2[c * 2 + 1]; }
    else              { int c = col - 192; b1 = bb1[c]; w0 = bw2[c * 2]; w1 = bw2[c * 2 + 1]; }
#pragma unroll
    for (int j = 0; j < 4; ++j) {
      float h = fmaxf(acc[ct][j] + b1, 0.f);
      float t0 = h * w0, t1 = h * w1;
      if (ct < 4)       { pg0[j] += t0; pg1[j] += t1; }
      else if (ct < 12) { pa0[j] += t0; pa1[j] += t1; }
      else              { pq0[j] += t0; pq1[j] += t1; }
    }
  }
#pragma unroll
  for (int m = 1; m < 16; m <<= 1)
#pragma unroll
    for (int j = 0; j < 4; ++j) {
      pg0[j] += __shfl_xor(pg0[j], m); pg1[j] += __shfl_xor(pg1[j], m);
      pa0[j] += __shfl_xor(pa0[j], m); pa1[j] += __shfl_xor(pa1[j], m);
      pq0[j] += __shfl_xor(pq0[j], m); pq1[j] += __shfl_xor(pq1[j], m);
    }
  if (lo == 0) {
#pragma unroll
    for (int j = 0; j < 4; ++j) {
      long grow = r0 + hi * 4 + j;
      float gl0 = pg0[j] + gb2[0], gl1 = pg1[j] + gb2[1];
      float fa0 = pa0[j] + ab2[0], fa1 = pa1[j] + ab2[1];
      float fb0 = pq0[j] + bb2[0], fb1 = pq1[j] + bb2[1];
      bool m0 = gl0 >= gl1;
      f32x4 o;
      o[0] = m0 ? fa0 : 0.f; o[1] = m0 ? fa1 : 0.f;
      o[2] = m0 ? 0.f : fb0; o[3] = m0 ? 0.f : fb1;
      *(f32x4*)(out + grow * 4) = o;
      float diff = gl0 - gl1;
      if (fabsf(diff) < TAU && cap > 0) {
        unsigned u = atomicAdd(cnt, 1u);
        if (u < (unsigned)cap) {
          unsigned* e = list + (size_t)u * 8;
          e[0] = (unsigned)grow;
          float* ef = (float*)(e + 4);
          ef[0] = fa0; ef[1] = fa1; ef[2] = fb0; ef[3] = fb1;
        }
      }
    }
  }
}

// ---- fixup: fp64 gate recompute for borderline rows (8 ILP chains) -----------
__global__ void moe_fixup(const float* __restrict__ x,
                          const float* __restrict__ gw1, const float* __restrict__ gb1,
                          const float* __restrict__ gw2, const float* __restrict__ gb2,
                          float* __restrict__ out, const unsigned* __restrict__ cnt,
                          const unsigned* __restrict__ list, int cap) {
  unsigned n = *cnt;
  if (n > (unsigned)cap) n = (unsigned)cap;
  const int l = threadIdx.x & 63;
  const int wid = blockIdx.x * (blockDim.x >> 6) + (threadIdx.x >> 6);
  const int nw = gridDim.x * (blockDim.x >> 6);
  for (unsigned e = wid; e < n; e += nw) {
    const unsigned* ent = list + (size_t)e * 8;
    unsigned row = ent[0];
    const float* ef = (const float*)(ent + 4);
    const float* xr0 = x + (long)row * 256;
    const float* xr1 = x + ((long)row + HALF_ROWS) * 256;
    double a[8] = {0, 0, 0, 0, 0, 0, 0, 0};
#pragma unroll 2
    for (int d = 0; d < 256; d += 8)
#pragma unroll
      for (int q = 0; q < 8; ++q)
        a[q] += (double)xr0[d + q] * (double)gw1[(d + q) * 64 + l];
#pragma unroll 2
    for (int d = 0; d < 256; d += 8)
#pragma unroll
      for (int q = 0; q < 8; ++q)
        a[q] += (double)xr1[d + q] * (double)gw1[(d + 256 + q) * 64 + l];
    double h = ((a[0] + a[1]) + (a[2] + a[3])) + ((a[4] + a[5]) + (a[6] + a[7]))
             + (double)gb1[l];
    h = h > 0.0 ? h : 0.0;
    double t0 = h * (double)gw2[l * 2];
    double t1 = h * (double)gw2[l * 2 + 1];
#pragma unroll
    for (int m = 1; m < 64; m <<= 1) {
      t0 += __shfl_xor(t0, m);
      t1 += __shfl_xor(t1, m);
    }
    if (l == 0) {
      bool m0 = (t0 + (double)gb2[0]) >= (t1 + (double)gb2[1]);
      f32x4 o;
      o[0] = m0 ? ef[0] : 0.f; o[1] = m0 ? ef[1] : 0.f;
      o[2] = m0 ? 0.f : ef[2]; o[3] = m0 ? 0.f : ef[3];
      *(f32x4*)(out + (size_t)row * 4) = o;
    }
  }
}

extern "C" void kernel_launch(void* const* d_in, const int* in_sizes, int n_in,
                              void* d_out, int out_size, void* d_ws, size_t ws_size,
                              hipStream_t stream) {
  const float* x   = (const float*)d_in[0];
  const float* gw1 = (const float*)d_in[1];
  const float* gb1 = (const float*)d_in[2];
  const float* gw2 = (const float*)d_in[3];
  const float* gb2 = (const float*)d_in[4];
  const float* aw1 = (const float*)d_in[5];
  const float* ab1 = (const float*)d_in[6];
  const float* aw2 = (const float*)d_in[7];
  const float* ab2 = (const float*)d_in[8];
  const float* bw1 = (const float*)d_in[9];
  const float* bb1 = (const float*)d_in[10];
  const float* bw2 = (const float*)d_in[11];
  const float* bb2 = (const float*)d_in[12];
  float* out = (float*)d_out;

  unsigned char* ws = (unsigned char*)d_ws;
  unsigned* cnt = (unsigned*)ws;
  unsigned short* Bf = (unsigned short*)(ws + BT_OFF);
  unsigned* list = (unsigned*)(ws + LIST_OFF);
  long cap_l = ((long)ws_size - (long)LIST_OFF) / 32;
  int cap = cap_l < 0 ? 0 : (cap_l > 262144 ? 262144 : (int)cap_l);

  moe_prep<<<320, 512, 0, stream>>>(gw1, aw1, bw1, Bf, cnt);
  moe_main<<<2048, 512, 0, stream>>>(x, Bf, gb1, gw2, gb2, ab1, aw2, ab2,
                                     bb1, bw2, bb2, out, cnt, list, cap);
  moe_fixup<<<2048, 256, 0, stream>>>(x, gw1, gb1, gw2, gb2, out, cnt, list, cap);
}

// Round 15
// 382.121 us; speedup vs baseline: 1.1012x; 1.1012x over previous
//
#include <hip/hip_runtime.h>
#include <hip/hip_bf16.h>

#define HALF_ROWS 262144
#define TAU 0.04f
#define BT_OFF 1024
#define LIST_OFF 328704              // BT_OFF + 320*512*2
#define PART_OFF 16777216            // 16MB; partials 2 x 262144 x 32B = 16.8MB
#define CAP 262144                   // (PART_OFF - LIST_OFF)/32 > 262144? 8MB/32=262144 ok

typedef __attribute__((ext_vector_type(8))) short s16x8;
typedef __attribute__((ext_vector_type(4))) float f32x4;

__device__ __forceinline__ unsigned short f2bf(float f) {
  union { float f; unsigned u; } v; v.f = f;
  unsigned r = v.u + 0x7fffu + ((v.u >> 16) & 1u);   // RTNE
  return (unsigned short)(r >> 16);
}

__device__ __forceinline__ s16x8 cvt8(const f32x4& a, const f32x4& b) {
  union { int i[4]; s16x8 v; } u;
  asm("v_cvt_pk_bf16_f32 %0, %1, %2" : "=v"(u.i[0]) : "v"(a[0]), "v"(a[1]));
  asm("v_cvt_pk_bf16_f32 %0, %1, %2" : "=v"(u.i[1]) : "v"(a[2]), "v"(a[3]));
  asm("v_cvt_pk_bf16_f32 %0, %1, %2" : "=v"(u.i[2]) : "v"(b[0]), "v"(b[1]));
  asm("v_cvt_pk_bf16_f32 %0, %1, %2" : "=v"(u.i[3]) : "v"(b[2]), "v"(b[3]));
  return u.v;
}

// ---- prep: W1 -> Bf in MFMA B-fragment order [cb20][ks16][lane64][8] ---------
__global__ void moe_prep(const float* __restrict__ gw1, const float* __restrict__ aw1,
                         const float* __restrict__ bw1, unsigned short* __restrict__ Bf,
                         unsigned* __restrict__ cnt) {
  if (blockIdx.x == 0 && threadIdx.x == 0) *cnt = 0u;
  int idx = blockIdx.x * 512 + threadIdx.x;          // 320*512 = 163840
  int j = idx & 7, l = (idx >> 3) & 63, ks = (idx >> 9) & 15, cb = idx >> 13;
  int col = cb * 16 + (l & 15);
  int k = ks * 32 + ((l >> 4) << 3) + j;
  float v;
  if (col < 64)       v = gw1[k * 64 + col];
  else if (col < 192) v = aw1[k * 128 + (col - 64)];
  else                v = bw1[k * 128 + (col - 192)];
  Bf[idx] = f2bf(v);
}

// ---- main: col-split 2. Block = 160 cols (entire B-half in 160KB LDS, loaded
// once) x 2048 rows. After one barrier, 8 waves FREE-RUN: per 16-row group the
// wave's vmcnt FIFO contains ONLY its 32 A-loads (B via ds_read = lgkmcnt), so
// A-prefetch stays 32KB deep. Partials (6 f32/row) to ws; combine merges.
__global__ __launch_bounds__(512, 2) void moe_main(
    const float* __restrict__ x, const unsigned short* __restrict__ Bf,
    const float* __restrict__ gb1, const float* __restrict__ gw2,
    const float* __restrict__ ab1, const float* __restrict__ aw2,
    const float* __restrict__ bb1, const float* __restrict__ bw2,
    float* __restrict__ part) {
  __shared__ unsigned short BL[81920];        // 160KB: [ct10][ks16][l64][8]

  const int tid = threadIdx.x;
  const int bid = blockIdx.x;
  const int ch = bid & 1;                     // col-half
  const long rb = (long)(bid >> 1) * 2048;
  const int w = tid >> 6, l = tid & 63;
  const int lo = l & 15, hi = l >> 4;

  // ---- load this half's B into LDS (once) ----
  {
    const unsigned short* src = Bf + ch * 81920;
#pragma unroll
    for (int i = 0; i < 20; ++i) {
      int q = tid + i * 512;                  // 10240 16B-chunks
      *(s16x8*)(BL + q * 8) = *(const s16x8*)(src + q * 8);
    }
  }
  __syncthreads();                            // the ONLY barrier

  // ---- per-ct epilogue constants (hoisted out of the group loop) ----
  float b1v[10], w0v[10], w1v[10];
  int head[10];
#pragma unroll
  for (int ct = 0; ct < 10; ++ct) {
    int c0 = ch * 160 + ct * 16;
    int col = c0 + lo;
    int hd = c0 < 64 ? 0 : (c0 < 192 ? 1 : 2);
    head[ct] = hd;
    if (hd == 0)      { b1v[ct] = gb1[col];           w0v[ct] = gw2[col * 2];       w1v[ct] = gw2[col * 2 + 1]; }
    else if (hd == 1) { int c = col - 64;  b1v[ct] = ab1[c]; w0v[ct] = aw2[c * 2]; w1v[ct] = aw2[c * 2 + 1]; }
    else              { int c = col - 192; b1v[ct] = bb1[c]; w0v[ct] = bw2[c * 2]; w1v[ct] = bw2[c * 2 + 1]; }
  }

#pragma unroll 1
  for (int g = 0; g < 16; ++g) {
    const long r0 = rb + g * 128 + w * 16;
    const float* b0 = x + (r0 + lo) * 256 + hi * 8;
    const float* b1 = b0 + (long)HALF_ROWS * 256;

    // ---- issue the whole group's A (32 independent 16B wave-loads) ----
    f32x4 s[32];
#pragma unroll
    for (int ks = 0; ks < 16; ++ks) {
      const float* p = (ks < 8) ? (b0 + ks * 32) : (b1 + (ks - 8) * 32);
      s[2 * ks]     = *(const f32x4*)p;
      s[2 * ks + 1] = *(const f32x4*)(p + 4);
    }

    f32x4 acc[10];
#pragma unroll
    for (int ct = 0; ct < 10; ++ct) acc[ct] = (f32x4){0.f, 0.f, 0.f, 0.f};

    // ---- consume: descending vmcnt waits (compiler), B via lgkmcnt only ----
#pragma unroll
    for (int ks = 0; ks < 16; ++ks) {
      s16x8 af = cvt8(s[2 * ks], s[2 * ks + 1]);
#pragma unroll
      for (int ct = 0; ct < 10; ++ct) {
        s16x8 bf = *(const s16x8*)(BL + ((ct * 16 + ks) * 64 + l) * 8);
        acc[ct] = __builtin_amdgcn_mfma_f32_16x16x32_bf16(af, bf, acc[ct], 0, 0, 0);
      }
    }

    // ---- epilogue: bias+relu+L2 heads -> 6-f32 partials ----
    float pg0[4] = {0,0,0,0}, pg1[4] = {0,0,0,0};
    float pa0[4] = {0,0,0,0}, pa1[4] = {0,0,0,0};
    float pq0[4] = {0,0,0,0}, pq1[4] = {0,0,0,0};
#pragma unroll
    for (int ct = 0; ct < 10; ++ct)
#pragma unroll
      for (int j = 0; j < 4; ++j) {
        float h = fmaxf(acc[ct][j] + b1v[ct], 0.f);
        float t0 = h * w0v[ct], t1 = h * w1v[ct];
        if (head[ct] == 0)      { pg0[j] += t0; pg1[j] += t1; }
        else if (head[ct] == 1) { pa0[j] += t0; pa1[j] += t1; }
        else                    { pq0[j] += t0; pq1[j] += t1; }
      }
#pragma unroll
    for (int m = 1; m < 16; m <<= 1)
#pragma unroll
      for (int j = 0; j < 4; ++j) {
        pg0[j] += __shfl_xor(pg0[j], m); pg1[j] += __shfl_xor(pg1[j], m);
        pa0[j] += __shfl_xor(pa0[j], m); pa1[j] += __shfl_xor(pa1[j], m);
        pq0[j] += __shfl_xor(pq0[j], m); pq1[j] += __shfl_xor(pq1[j], m);
      }
    if (lo == 0) {
#pragma unroll
      for (int j = 0; j < 4; ++j) {
        long r = r0 + hi * 4 + j;
        float* pp = part + ((long)ch * 262144 + r) * 8;
        pp[0] = pg0[j]; pp[1] = pg1[j]; pp[2] = pa0[j];
        pp[3] = pa1[j]; pp[4] = pq0[j]; pp[5] = pq1[j];
      }
    }
  }
}

// ---- combine: merge halves, gate, write out, queue TAU fixup list ------------
__global__ void moe_combine(const float* __restrict__ part,
                            const float* __restrict__ gb2, const float* __restrict__ ab2,
                            const float* __restrict__ bb2, float* __restrict__ out,
                            unsigned* __restrict__ cnt, unsigned* __restrict__ list, int cap) {
  long r = (long)blockIdx.x * 256 + threadIdx.x;
  const float* p0 = part + r * 8;
  const float* p1 = part + (262144L + r) * 8;
  float gl0 = p0[0] + gb2[0], gl1 = p0[1] + gb2[1];
  float fa0 = p0[2] + p1[2] + ab2[0], fa1 = p0[3] + p1[3] + ab2[1];
  float fb0 = p1[4] + bb2[0], fb1 = p1[5] + bb2[1];
  bool m0 = gl0 >= gl1;
  f32x4 o;
  o[0] = m0 ? fa0 : 0.f; o[1] = m0 ? fa1 : 0.f;
  o[2] = m0 ? 0.f : fb0; o[3] = m0 ? 0.f : fb1;
  *(f32x4*)(out + r * 4) = o;
  float diff = gl0 - gl1;
  if (fabsf(diff) < TAU && cap > 0) {
    unsigned u = atomicAdd(cnt, 1u);
    if (u < (unsigned)cap) {
      unsigned* e = list + (size_t)u * 8;
      e[0] = (unsigned)r;
      float* ef = (float*)(e + 4);
      ef[0] = fa0; ef[1] = fa1; ef[2] = fb0; ef[3] = fb1;
    }
  }
}

// ---- fixup: fp64 gate recompute for borderline rows (8 ILP chains) -----------
__global__ void moe_fixup(const float* __restrict__ x,
                          const float* __restrict__ gw1, const float* __restrict__ gb1,
                          const float* __restrict__ gw2, const float* __restrict__ gb2,
                          float* __restrict__ out, const unsigned* __restrict__ cnt,
                          const unsigned* __restrict__ list, int cap) {
  unsigned n = *cnt;
  if (n > (unsigned)cap) n = (unsigned)cap;
  const int l = threadIdx.x & 63;
  const int wid = blockIdx.x * (blockDim.x >> 6) + (threadIdx.x >> 6);
  const int nw = gridDim.x * (blockDim.x >> 6);
  for (unsigned e = wid; e < n; e += nw) {
    const unsigned* ent = list + (size_t)e * 8;
    unsigned row = ent[0];
    const float* ef = (const float*)(ent + 4);
    const float* xr0 = x + (long)row * 256;
    const float* xr1 = x + ((long)row + HALF_ROWS) * 256;
    double a[8] = {0, 0, 0, 0, 0, 0, 0, 0};
#pragma unroll 2
    for (int d = 0; d < 256; d += 8)
#pragma unroll
      for (int q = 0; q < 8; ++q)
        a[q] += (double)xr0[d + q] * (double)gw1[(d + q) * 64 + l];
#pragma unroll 2
    for (int d = 0; d < 256; d += 8)
#pragma unroll
      for (int q = 0; q < 8; ++q)
        a[q] += (double)xr1[d + q] * (double)gw1[(d + 256 + q) * 64 + l];
    double h = ((a[0] + a[1]) + (a[2] + a[3])) + ((a[4] + a[5]) + (a[6] + a[7]))
             + (double)gb1[l];
    h = h > 0.0 ? h : 0.0;
    double t0 = h * (double)gw2[l * 2];
    double t1 = h * (double)gw2[l * 2 + 1];
#pragma unroll
    for (int m = 1; m < 64; m <<= 1) {
      t0 += __shfl_xor(t0, m);
      t1 += __shfl_xor(t1, m);
    }
    if (l == 0) {
      bool m0 = (t0 + (double)gb2[0]) >= (t1 + (double)gb2[1]);
      f32x4 o;
      o[0] = m0 ? ef[0] : 0.f; o[1] = m0 ? ef[1] : 0.f;
      o[2] = m0 ? 0.f : ef[2]; o[3] = m0 ? 0.f : ef[3];
      *(f32x4*)(out + (size_t)row * 4) = o;
    }
  }
}

extern "C" void kernel_launch(void* const* d_in, const int* in_sizes, int n_in,
                              void* d_out, int out_size, void* d_ws, size_t ws_size,
                              hipStream_t stream) {
  const float* x   = (const float*)d_in[0];
  const float* gw1 = (const float*)d_in[1];
  const float* gb1 = (const float*)d_in[2];
  const float* gw2 = (const float*)d_in[3];
  const float* gb2 = (const float*)d_in[4];
  const float* aw1 = (const float*)d_in[5];
  const float* ab1 = (const float*)d_in[6];
  const float* aw2 = (const float*)d_in[7];
  const float* ab2 = (const float*)d_in[8];
  const float* bw1 = (const float*)d_in[9];
  const float* bb1 = (const float*)d_in[10];
  const float* bw2 = (const float*)d_in[11];
  const float* bb2 = (const float*)d_in[12];
  float* out = (float*)d_out;

  unsigned char* ws = (unsigned char*)d_ws;
  unsigned* cnt = (unsigned*)ws;
  unsigned short* Bf = (unsigned short*)(ws + BT_OFF);
  unsigned* list = (unsigned*)(ws + LIST_OFF);
  float* part = (float*)(ws + PART_OFF);
  int cap = (ws_size >= PART_OFF + 2L * 262144 * 32) ? CAP : 0;

  moe_prep<<<320, 512, 0, stream>>>(gw1, aw1, bw1, Bf, cnt);
  moe_main<<<256, 512, 0, stream>>>(x, Bf, gb1, gw2, ab1, aw2, bb1, bw2, part);
  moe_combine<<<1024, 256, 0, stream>>>(part, gb2, ab2, bb2, out, cnt, list, cap);
  moe_fixup<<<2048, 256, 0, stream>>>(x, gw1, gb1, gw2, gb2, out, cnt, list, cap);
}